// Round 14
// baseline (169.166 us; speedup 1.0000x reference)
//
#include <hip/hip_runtime.h>
#include <stdint.h>

// FixedConv1DPriorEnsemble: DZ=30 ensemble of conv nets over embedded tokens.
// V=32000 E=8 DZ=30 C=10, CH=(4,8,8), K=3, S=(2,2,1), B=512, L=4096.
//
// History: R15 243.4; R16 1695 CATASTROPHIC (cross-XCD fences); R22 201.0
//   (d-PAIR @512thr); R23 187.2 (d-QUAD @1024thr); R24 342.6 CATASTROPHIC
//   (token-major x -> VMEM scatter); R25 186.3; R26 182.3; R27 174.8 (h2
//   pair-interleave); R28 171.0 (unwrapped h1 rot, conflicts -> 2.0M);
//   R29 168.5 (dead-wave guards, 4 barriers); R30 164.4 (packed cvt+relu,
//   union B-frags, hoisted guard: ensemble 72.5, VALU 52%).
// R31: PREP stores. Evidence: prep never appears in top-5 dispatches
//   (=> < 72us) yet gap ~92us; prep's 1-tok/thread layout costs 8 scalar
//   b16 stores/thread = 16M store instrs chip-wide -- the likely floor.
//   Now 8 consecutive tokens/thread: each gathered table row is consumed
//   immediately into 8 f16x8 e-plane accumulators (all-static indexing;
//   no f32 staging array -- R20's regression was its vals[8][8] spill),
//   then 8x 16B coalesced stores (store instrs 16M -> 2M, gathers
//   unchanged, per-thread gather ILP 16 outstanding). x layout and the
//   ensemble kernel are UNTOUCHED (R24 lesson: lane-contiguous A loads
//   are sacred). Numerics bit-identical (same scalar RTN converts).

typedef _Float16 f16;
typedef f16 f16x2 __attribute__((ext_vector_type(2)));
typedef f16 f16x4 __attribute__((ext_vector_type(4)));
typedef f16 f16x8 __attribute__((ext_vector_type(8)));
typedef float f32x4 __attribute__((ext_vector_type(4)));

#define H1ROWC 528   // h1 row size in f16x4 chunks (rot_max 15 + 513)
#define H1REGC 2112  // h1 region size in chunks (4 rows)
#define REGH   8448  // region size in f16 (= H1REGC*4); h2 uses 8224 of it
#define H2RS   2056  // h2 pair-row stride in f16 (4112B: 1024 cells + 16B pad)

// packed f32x2 -> f16x2 convert (RTZ) + packed ReLU
static __device__ __forceinline__ f16x2 cvtpk_relu(float a, float b) {
  auto r = __builtin_amdgcn_cvt_pkrtz(a, b);
  union { decltype(r) i; f16x2 o; } u; u.i = r;
  const f16x2 z2 = {(f16)0.0f, (f16)0.0f};
  return __builtin_elementwise_max(u.o, z2);   // v_pk_max_f16
}

// ---- prep: embed x_f16 (e-major) + stage-1 quad B-frags + a2/a3 ----
__global__ __launch_bounds__(256) void prep_kernel(
    const int* __restrict__ ids, const float* __restrict__ mask,
    const float* __restrict__ tbl,
    const float* __restrict__ W1, const float* __restrict__ W2,
    const float* __restrict__ W3,
    f16* __restrict__ x, f16* __restrict__ a1q,
    f16* __restrict__ a2, f16* __restrict__ a3) {
  const int blk = blockIdx.x;
  if (blk < 1024) {                            // embed: 8 tokens/thread
    const int gidx = blk * 256 + threadIdx.x;  // 0..262143
    const int b  = gidx >> 9;                  // 0..511
    const int l0 = (gidx & 511) * 8;           // 0..4088
    const int*   idp = ids  + (size_t)b * 4096 + l0;
    const float* mp  = mask + (size_t)b * 4096 + l0;
    const int4   iv0 = *(const int4*)idp,  iv1 = *(const int4*)(idp + 4);
    const float4 mv0 = *(const float4*)mp, mv1 = *(const float4*)(mp + 4);
    const int   idt[8] = {iv0.x, iv0.y, iv0.z, iv0.w,
                          iv1.x, iv1.y, iv1.z, iv1.w};
    const float mt[8]  = {mv0.x, mv0.y, mv0.z, mv0.w,
                          mv1.x, mv1.y, mv1.z, mv1.w};
    const float4* t4 = (const float4*)tbl;
    f16x8 acc[8];                              // [e] -> 8 tokens, 32 VGPRs
    #pragma unroll
    for (int k = 0; k < 8; ++k) {              // consume each row immediately
      const float4 va = t4[(size_t)idt[k] * 2];
      const float4 vb = t4[(size_t)idt[k] * 2 + 1];
      const float r[8] = {va.x, va.y, va.z, va.w, vb.x, vb.y, vb.z, vb.w};
      #pragma unroll
      for (int e = 0; e < 8; ++e)
        acc[e][k] = (f16)(r[e] * mt[k]);       // RTN, identical to before
    }
    f16* xb = x + (size_t)b * 32768 + l0;      // e-major: [b][e][4096]
    #pragma unroll
    for (int e = 0; e < 8; ++e)
      *(f16x8*)(xb + e * 4096) = acc[e];       // 16B store, lane stride 16B
  } else {
    const int i = (blk - 1024) * 256 + threadIdx.x;
    if (i < 512) {                             // a1q: 8 groups * 64 lanes
      // Stage-1 B-frag (E-MAJOR K-map): k = kg*8+j ->
      //   e = 2*kg + (j>>2), tap = j&3 (tap==3 slots zero: K pad 24->32).
      const int g = i >> 6, l = i & 63;
      const int kg = l >> 4, col = l & 15;
      const int d = 4 * g + (col >> 2);
      f16x8 v;
      #pragma unroll
      for (int j = 0; j < 8; ++j) {
        const int e = 2 * kg + (j >> 2), tap = j & 3;
        float val = 0.0f;
        if (tap < 3 && d < 30)
          val = W1[d * 96 + (col & 3) * 24 + e * 3 + tap];
        v[j] = (f16)val;
      }
      *(f16x8*)(a1q + ((size_t)g * 64 + l) * 8) = v;
    } else if (i < 2432) {                     // a2: 30*64
      const int idx = i - 512, d = idx >> 6, lane = idx & 63;
      const int quad = lane >> 4, m = lane & 15;
      f16x8 v;
      #pragma unroll
      for (int j = 0; j < 8; ++j) {
        float val = 0.0f;
        if (m < 8)  { if (j < 3)           val = W2[d * 96 + m * 12 + quad * 3 + j]; }
        else        { if (j >= 2 && j < 5) val = W2[d * 96 + (m - 8) * 12 + quad * 3 + (j - 2)]; }
        v[j] = (f16)val;
      }
      *(f16x8*)(a2 + ((size_t)d * 64 + lane) * 8) = v;
    } else if (i < 4352) {                     // a3: 30*64 (PAIR K-map)
      // K-slot j: row-sel = j&1 (c2 = quad*2 + (j&1)), tap index t = j>>1.
      const int idx = i - 2432, d = idx >> 6, lane = idx & 63;
      const int quad = lane >> 4, m = lane & 15;
      f16x8 v;
      #pragma unroll
      for (int j = 0; j < 8; ++j) {
        const int c2 = quad * 2 + (j & 1), t = j >> 1;
        float val = 0.0f;
        if (m < 8)  { if (t < 3)  val = W3[d * 192 + m * 24 + c2 * 3 + t]; }
        else        { if (t >= 1) val = W3[d * 192 + (m - 8) * 24 + c2 * 3 + (t - 1)]; }
        v[j] = (f16)val;
      }
      *(f16x8*)(a3 + ((size_t)d * 64 + lane) * 8) = v;
    }
  }
}

// ---------- fast path: one 1024-thread block per (b, d-quad group) ----------
__global__ __launch_bounds__(1024, 8) void ensemble_f16_kernel(
    const f16* __restrict__ x,        // [512][8][4096]  (e-major)
    const f16* __restrict__ a1q,      // stage-1 B-frags [8][64][8]
    const f16* __restrict__ a2,       // stage-2 A-frags [30][64][8]
    const f16* __restrict__ a3,       // stage-3 A-frags [30][64][8] (pair map)
    const float* __restrict__ z,
    const float* __restrict__ b1, const float* __restrict__ b2,
    const float* __restrict__ b3,
    const float* __restrict__ Wh, const float* __restrict__ bh,
    float* __restrict__ part)         // [30][512][10]
{
  const int tid = threadIdx.x;
  // XCD-bijective swizzle: 4096 = 8 XCDs x 512. All 8 same-b groups (and 64
  // consecutive b's) land on one XCD -> x row lives in that XCD's L2.
  const int swz = ((blockIdx.x & 7) * 512) + (blockIdx.x >> 3);
  const int b   = swz >> 3;           // 0..511
  const int G   = swz & 7;            // d-quad group: d = 4G .. 4G+3 (G=7: pair)
  const int d_base = 4 * G;

  // LDS: 4 regions x REGH f16 = 67584B + red2 512B.
  //   region g, h1: 4 rows x 528 chunks (f16x4); row data starts at chunk
  //     offset rot = row + 4*g; chunk rot+512 pre-zeroed (stage-2 +1 read).
  //   h2 overlay (post-B2): pair rows rp=0..3, stride H2RS f16.
  __shared__ __align__(16) f16 smemh[4 * REGH];
  __shared__ float red2[128];         // [4 groups][32]; NOT overlaid -> no B4

  const int w = tid >> 6, lane = tid & 63, quad = lane >> 4, n = lane & 15;
  const int gg = w >> 2, wv = w & 3;  // wave-group (d within quad), wave-in-group
  const int d  = d_base + gg;
  const int dc = d < 30 ? d : 29;     // clamp (loads before the live-guards)
  const bool live = (d < 30);         // G=7 gg=2,3: dead for stages 2/3

  // pre-zero the 16 read-but-never-written tail chunks (rot+512 per row)
  if (tid < 16) {
    f16x4 zz = {(f16)0.0f, (f16)0.0f, (f16)0.0f, (f16)0.0f};
    ((f16x4*)smemh)[(tid >> 2) * H1REGC + (tid & 3) * H1ROWC + tid + 512] = zz;
  }

  // ---- stage 1 (MFMA, ALL 16 waves, 4 d's): 128 tiles of 16 positions ----
  // A = patches (E-MAJOR): lane(row=n, kg=quad) holds x[e=2q..2q+1][2*pos+0..3],
  //   pos = 16t + n; tap-3 K-slots hit zero weights (x finite, no masking).
  // B = a1q (cols 0-15 = 4d x 4ch). D: lane(col=n, quad) -> one b64 write at
  //   chunk rot + 4t + quad, rot = n. Banks: (n+4t+q) mod 16 = perfect floor.
  // Position 2047 tail garbage-finite (feeds only masked jl=1023 column);
  //   b=511 tail over-read lands in a1q (allocated, finite).
  {
    const f16x8 bw1 = *(const f16x8*)(a1q + ((size_t)G * 64 + lane) * 8);
    const int dn  = d_base + (n >> 2);
    const int dnc = dn < 30 ? dn : 29;
    const float bias = b1[dnc * 4 + (n & 3)];
    const f32x4 c1i = {bias, bias, bias, bias};
    const char* xc = (const char*)x + (size_t)b * 65536 + quad * 16384 + 4 * n;
    f16x4* h1c = (f16x4*)smemh + (n >> 2) * H1REGC + (n & 3) * H1ROWC + n;
    #pragma unroll
    for (int i = 0; i < 8; ++i) {
      const int t = w + 16 * i;                // 0..127
      const uint32_t o = 64u * (uint32_t)t;
      union { f16x8 v; uint32_t dw[4]; } u;
      u.dw[0] = *(const uint32_t*)(xc + o);            // e0: taps 0,1
      u.dw[1] = *(const uint32_t*)(xc + o + 4);        // e0: tap 2 (+dead)
      u.dw[2] = *(const uint32_t*)(xc + o + 8192);     // e1: taps 0,1
      u.dw[3] = *(const uint32_t*)(xc + o + 8192 + 4); // e1: tap 2 (+dead)
      const f32x4 D = __builtin_amdgcn_mfma_f32_16x16x32_f16(u.v, bw1, c1i, 0, 0, 0);
      union { f16x4 p; f16x2 h[2]; } up;
      up.h[0] = cvtpk_relu(D[0], D[1]);        // v_cvt_pkrtz + v_pk_max
      up.h[1] = cvtpk_relu(D[2], D[3]);
      h1c[4 * t + quad] = up.p;                // ds_write_b64, mask-free
    }
  }
  __syncthreads();                     // B1: h1 writes -> h1 reads

  // ---- stage 2 (MFMA): wave-group gg handles d on region gg; 32 tiles ----
  // B-frag = h1[row=quad][chunks 16t+n, 16t+n+1] at offset rot = quad+4*gg.
  //   The +1 at t=31,n=15 reads the pre-zeroed chunk rot+512 (j>=5 zero-
  //   weighted for m<8; j=4 feeds only the masked jl=1023 column).
  f32x4 Ci[8];
  if (live) {
    const f16x8 af2 = *(const f16x8*)(a2 + ((size_t)dc * 64 + lane) * 8);
    const f32x4 cinit2 = *(const f32x4*)(b2 + dc * 8 + (quad & 1) * 4);
    const f16x4* h1r = (const f16x4*)smemh + gg * H1REGC + quad * H1ROWC
                     + (quad + 4 * gg);
    #pragma unroll
    for (int i = 0; i < 8; ++i) {
      const int t = wv + 4 * i;               // 0..31
      union { f16x8 v; f16x4 h[2]; } u;      // adjacent halves, no shuffle
      u.h[0] = h1r[16 * t + n];
      u.h[1] = h1r[16 * t + n + 1];
      Ci[i] = __builtin_amdgcn_mfma_f32_16x16x32_f16(af2, u.v, cinit2, 0, 0, 0);
    }
  }
  __syncthreads();                     // B2: all h1 reads done; overlay h2

  // ---- h2 write (pair cells): rows c2b..c2b+3 -> pairs rp0, rp0+1 at
  //   position jl = 32t+2n+shift; two packed ds_write_b32, rotation-free.
  if (live) {
    f16* h2b = smemh + gg * REGH;
    const int rp0   = (quad & 1) * 2;
    const int shift = quad >> 1;
    #pragma unroll
    for (int i = 0; i < 8; ++i) {
      const int t  = wv + 4 * i;
      const int jl = 32 * t + 2 * n + shift;   // 0..1023
      const f16x2 pA = cvtpk_relu(Ci[i][0], Ci[i][1]);
      const f16x2 pB = cvtpk_relu(Ci[i][2], Ci[i][3]);
      *(f16x2*)(h2b + rp0 * H2RS + jl * 2)       = pA;
      *(f16x2*)(h2b + (rp0 + 1) * H2RS + jl * 2) = pB;
    }
  }
  __syncthreads();                     // B3: h2 writes -> h2 reads

  // ---- stage 3 (MFMA) + pool + reduction (no barrier after: red2 disjoint) ----
  if (live) {
    float pool4[4] = {0.0f, 0.0f, 0.0f, 0.0f};
    const f16x8 af3 = *(const f16x8*)(a3 + ((size_t)dc * 64 + lane) * 8);
    const f32x4 cinit3 = *(const f32x4*)(b3 + dc * 8 + (quad & 1) * 4);
    const f16* h2r = smemh + gg * REGH + quad * H2RS;
    #pragma unroll
    for (int i = 0; i < 8; ++i) {
      const int t  = wv + 4 * i;              // 0..31
      const int p0 = 32 * t + 2 * n;          // 0..1022 (even)
      union { f16x8 v; f16x4 h[2]; } u;      // adjacent halves, no shuffle
      u.h[0] = *(const f16x4*)(h2r + p0 * 2);      // cells p0,p0+1
      u.h[1] = *(const f16x4*)(h2r + p0 * 2 + 4);  // cells p0+2,p0+3
      const f32x4 C = __builtin_amdgcn_mfma_f32_16x16x32_f16(af3, u.v, cinit3, 0, 0, 0);
      if (i < 7) {                            // pl = 32t+2n+s <= 895 < 1021
        #pragma unroll
        for (int r = 0; r < 4; ++r) pool4[r] += fmaxf(C[r], 0.0f);
      } else {
        const int pl = 32 * t + 2 * n + (quad >> 1);
        if (pl < 1021) {
          #pragma unroll
          for (int r = 0; r < 4; ++r) pool4[r] += fmaxf(C[r], 0.0f);
        }
      }
    }
    // shfl_xor butterfly over the 32 lanes sharing a cc-group (masks
    // 1,2,4,8,32 never touch lane bit 4); one write per (wave, cc-group).
    #pragma unroll
    for (int r = 0; r < 4; ++r) pool4[r] += __shfl_xor(pool4[r], 1, 64);
    #pragma unroll
    for (int r = 0; r < 4; ++r) pool4[r] += __shfl_xor(pool4[r], 2, 64);
    #pragma unroll
    for (int r = 0; r < 4; ++r) pool4[r] += __shfl_xor(pool4[r], 4, 64);
    #pragma unroll
    for (int r = 0; r < 4; ++r) pool4[r] += __shfl_xor(pool4[r], 8, 64);
    #pragma unroll
    for (int r = 0; r < 4; ++r) pool4[r] += __shfl_xor(pool4[r], 32, 64);
    if ((lane & 47) == 0) {      // lanes 0 (cc 0-3) and 16 (cc 4-7)
      const int cg = (lane >> 4) & 1;
      #pragma unroll
      for (int r = 0; r < 4; ++r)
        red2[gg * 32 + wv * 8 + cg * 4 + r] = pool4[r];
    }
  }
  __syncthreads();                     // B4: red2 writes -> head reads

  // ---- heads: waves 0,4,8,12 -> d = d_base + gg ----
  if ((w & 3) == 0 && lane < 10 && live) {
    float acc = bh[d * 10 + lane];
    #pragma unroll
    for (int c3 = 0; c3 < 8; ++c3) {
      const float pooled = red2[gg * 32 + c3]      + red2[gg * 32 + 8 + c3]
                         + red2[gg * 32 + 16 + c3] + red2[gg * 32 + 24 + c3];
      acc = fmaf(pooled * (1.0f / 1021.0f), Wh[d * 80 + lane * 8 + c3], acc);
    }
    part[((size_t)d * 512 + b) * 10 + lane] = z[d] * acc;
  }
}

// Fixed-order reduction over 30 d-partials: bitwise-deterministic.
__global__ __launch_bounds__(256) void reduce30_kernel(
    const float* __restrict__ part,   // [30][512][10]
    float* __restrict__ out)          // [512][10]
{
  const int i = blockIdx.x * 256 + threadIdx.x;   // 0..5119
  float s = 0.0f;
  #pragma unroll
  for (int dd = 0; dd < 30; ++dd) s += part[dd * 5120 + i];
  out[i] = s;
}

// ---------------- fallback path: exact R7 fp32 kernel (60 partials) ----------------
__global__ __launch_bounds__(256, 6) void ensemble_kernel(
    const int* __restrict__ ids, const float* __restrict__ mask,
    const float* __restrict__ z, const float* __restrict__ tbl,
    const float* __restrict__ W1, const float* __restrict__ b1,
    const float* __restrict__ W2, const float* __restrict__ b2,
    const float* __restrict__ W3, const float* __restrict__ b3,
    const float* __restrict__ Wh, const float* __restrict__ bh,
    float* __restrict__ part)
{
  const int tid  = threadIdx.x;
  const int half = blockIdx.x & 1;
  const int bd   = blockIdx.x >> 1;
  const int b    = bd & 511;
  const int d    = bd >> 9;

  __shared__ float smem[4128];
  __shared__ float red[32];
  __shared__ float pooled[8];

  const int l_lo = half ? 1024 : 0;
  const int l_hi = half ? 2047 : 1029;
  const int j_lo = half ? 512  : 0;
  const int j_hi = half ? 1023 : 514;
  const int o_lo = half ? 512  : 0;
  const int o_hi = half ? 1021 : 512;

  const int*    idrow = ids  + (size_t)b * 4096;
  const float*  mrow  = mask + (size_t)b * 4096;
  const float4* tbl4  = (const float4*)tbl;
  const float*  w1p = W1 + d * 96;
  const float*  w2p = W2 + d * 96;
  const float*  w3p = W3 + d * 192;

  {
    float bia[4];
    #pragma unroll
    for (int c = 0; c < 4; ++c) bia[c] = b1[d * 4 + c];

    #pragma unroll 1
    for (int pass = 0; pass < 2; ++pass) {
      const int l0 = l_lo + 2 * tid + 512 * pass;
      const int p0 = 2 * l0;
      const int4   iv = *(const int4*)(idrow + p0);
      const float4 mv = *(const float4*)(mrow + p0);
      int i4; float m4;
      if (p0 + 4 < 4096) { i4 = idrow[p0 + 4]; m4 = mrow[p0 + 4]; }
      else               { i4 = 0;              m4 = 0.0f; }

      const int   pid[5] = {iv.x, iv.y, iv.z, iv.w, i4};
      const float pm[5]  = {mv.x, mv.y, mv.z, mv.w, m4};

      float a0[4], a1v[4];
      #pragma unroll
      for (int c = 0; c < 4; ++c) { a0[c] = bia[c]; a1v[c] = bia[c]; }

      #pragma unroll
      for (int q = 0; q < 5; ++q) {
        const float4 va = tbl4[(size_t)pid[q] * 2];
        const float4 vb = tbl4[(size_t)pid[q] * 2 + 1];
        const float xe[8] = {va.x * pm[q], va.y * pm[q], va.z * pm[q], va.w * pm[q],
                             vb.x * pm[q], vb.y * pm[q], vb.z * pm[q], vb.w * pm[q]};
        if (q <= 2) {
          #pragma unroll
          for (int c = 0; c < 4; ++c)
            #pragma unroll
            for (int e = 0; e < 8; ++e)
              a0[c] = fmaf(xe[e], w1p[c * 24 + e * 3 + q], a0[c]);
        }
        if (q >= 2) {
          #pragma unroll
          for (int c = 0; c < 4; ++c)
            #pragma unroll
            for (int e = 0; e < 8; ++e)
              a1v[c] = fmaf(xe[e], w1p[c * 24 + e * 3 + (q - 2)], a1v[c]);
        }
      }
      const int rel = l0 - l_lo;
      if (l0 + 1 < l_hi) {
        #pragma unroll
        for (int c = 0; c < 4; ++c)
          *(float2*)(smem + c * 1032 + rel) =
              make_float2(fmaxf(a0[c], 0.0f), fmaxf(a1v[c], 0.0f));
      } else if (l0 < l_hi) {
        #pragma unroll
        for (int c = 0; c < 4; ++c)
          smem[c * 1032 + rel] = fmaxf(a0[c], 0.0f);
      }
    }
    const int lt = l_lo + 1024 + tid;
    if (lt < l_hi) {
      float a0[4];
      #pragma unroll
      for (int c = 0; c < 4; ++c) a0[c] = bia[c];
      #pragma unroll
      for (int k = 0; k < 3; ++k) {
        const int p = 2 * lt + k;
        const int id = idrow[p];
        const float m = mrow[p];
        const float4 va = tbl4[(size_t)id * 2];
        const float4 vb = tbl4[(size_t)id * 2 + 1];
        const float xe[8] = {va.x*m, va.y*m, va.z*m, va.w*m,
                             vb.x*m, vb.y*m, vb.z*m, vb.w*m};
        #pragma unroll
        for (int cc = 0; cc < 4; ++cc)
          #pragma unroll
          for (int e = 0; e < 8; ++e)
            a0[cc] = fmaf(xe[e], w1p[cc * 24 + e * 3 + k], a0[cc]);
      }
      #pragma unroll
      for (int c = 0; c < 4; ++c)
        smem[c * 1032 + 1024 + tid] = fmaxf(a0[c], 0.0f);
    }
  }
  __syncthreads();

  float acc2[8][2], acc2t[8];
  {
    #pragma unroll
    for (int c2 = 0; c2 < 8; ++c2) {
      const float bb = b2[d * 8 + c2];
      acc2[c2][0] = bb; acc2[c2][1] = bb; acc2t[c2] = bb;
    }
    const int rel2  = 4 * tid;
    const bool tail2 = tid < (j_hi - j_lo - 512);
    #pragma unroll 1
    for (int c1 = 0; c1 < 4; ++c1) {
      float sw[8][3];
      #pragma unroll
      for (int c2 = 0; c2 < 8; ++c2)
        #pragma unroll
        for (int kk = 0; kk < 3; ++kk)
          sw[c2][kk] = w2p[c2 * 12 + c1 * 3 + kk];
      const float* hp = smem + c1 * 1032;
      const float4 h01 = *(const float4*)(hp + rel2);
      const float  h4v = hp[rel2 + 4];
      #pragma unroll
      for (int c2 = 0; c2 < 8; ++c2) {
        acc2[c2][0] = fmaf(h01.x, sw[c2][0], fmaf(h01.y, sw[c2][1],
                      fmaf(h01.z, sw[c2][2], acc2[c2][0])));
        acc2[c2][1] = fmaf(h01.z, sw[c2][0], fmaf(h01.w, sw[c2][1],
                      fmaf(h4v,   sw[c2][2], acc2[c2][1])));
      }
      if (tail2) {
        const float t0 = hp[1024 + 2 * tid], t1 = hp[1025 + 2 * tid],
                    t2 = hp[1026 + 2 * tid];
        #pragma unroll
        for (int c2 = 0; c2 < 8; ++c2)
          acc2t[c2] = fmaf(t0, sw[c2][0], fmaf(t1, sw[c2][1],
                      fmaf(t2, sw[c2][2], acc2t[c2])));
      }
    }
    #pragma unroll
    for (int c2 = 0; c2 < 8; ++c2) {
      acc2[c2][0] = fmaxf(acc2[c2][0], 0.0f);
      acc2[c2][1] = fmaxf(acc2[c2][1], 0.0f);
      acc2t[c2]   = fmaxf(acc2t[c2],   0.0f);
    }
    __syncthreads();
    const int j0 = j_lo + 2 * tid;
    const int jr = 2 * tid;
    if (j0 + 1 < j_hi) {
      #pragma unroll
      for (int c2 = 0; c2 < 8; ++c2)
        *(float2*)(smem + c2 * 516 + jr) = make_float2(acc2[c2][0], acc2[c2][1]);
    } else if (j0 < j_hi) {
      #pragma unroll
      for (int c2 = 0; c2 < 8; ++c2)
        smem[c2 * 516 + jr] = acc2[c2][0];
    }
    if (tid < (j_hi - j_lo - 512)) {
      #pragma unroll
      for (int c2 = 0; c2 < 8; ++c2)
        smem[c2 * 516 + 512 + tid] = acc2t[c2];
    }
  }
  __syncthreads();

  float acc3[8][2];
  #pragma unroll
  for (int cc = 0; cc < 8; ++cc) {
    const float bb = b3[d * 8 + cc];
    acc3[cc][0] = bb; acc3[cc][1] = bb;
  }
  {
    const int rel3 = 2 * tid;
    #pragma unroll 1
    for (int c2 = 0; c2 < 8; ++c2) {
      float sw[8][3];
      #pragma unroll
      for (int cc = 0; cc < 8; ++cc)
        #pragma unroll
        for (int kk = 0; kk < 3; ++kk)
          sw[cc][kk] = w3p[cc * 24 + c2 * 3 + kk];
      const float* hp = smem + c2 * 516;
      const float2 ha = *(const float2*)(hp + rel3);
      const float2 hb = *(const float2*)(hp + rel3 + 2);
      #pragma unroll
      for (int cc = 0; cc < 8; ++cc) {
        acc3[cc][0] = fmaf(ha.x, sw[cc][0], fmaf(ha.y, sw[cc][1],
                      fmaf(hb.x, sw[cc][2], acc3[cc][0])));
        acc3[cc][1] = fmaf(ha.y, sw[cc][0], fmaf(hb.x, sw[cc][1],
                      fmaf(hb.y, sw[cc][2], acc3[cc][1])));
      }
    }
  }
  const int i0 = o_lo + 2 * tid;
  float psum[8];
  #pragma unroll
  for (int cc = 0; cc < 8; ++cc) {
    float s = 0.0f;
    if (i0 < o_hi)     s += fmaxf(acc3[cc][0], 0.0f);
    if (i0 + 1 < o_hi) s += fmaxf(acc3[cc][1], 0.0f);
    psum[cc] = s;
  }

  const int lane = tid & 63;
  const int wid  = tid >> 6;
  #pragma unroll
  for (int c = 0; c < 8; ++c) {
    float v = psum[c];
    #pragma unroll
    for (int off = 32; off > 0; off >>= 1) v += __shfl_down(v, off, 64);
    if (lane == 0) red[wid * 8 + c] = v;
  }
  __syncthreads();
  if (tid < 8)
    pooled[tid] = red[tid] + red[8 + tid] + red[16 + tid] + red[24 + tid];
  __syncthreads();

  if (tid < 10) {
    float acc = (half == 0) ? bh[d * 10 + tid] : 0.0f;
    #pragma unroll
    for (int c3 = 0; c3 < 8; ++c3)
      acc = fmaf(pooled[c3] * (1.0f / 1021.0f), Wh[d * 80 + tid * 8 + c3], acc);
    part[(((size_t)d * 2 + half) * 512 + b) * 10 + tid] = z[d] * acc;
  }
}

__global__ __launch_bounds__(256) void reduce60_kernel(
    const float* __restrict__ part,   // [60][512][10]
    float* __restrict__ out)          // [512][10]
{
  const int i = blockIdx.x * 256 + threadIdx.x;
  float s = 0.0f;
  #pragma unroll
  for (int dd = 0; dd < 60; ++dd) s += part[dd * 5120 + i];
  out[i] = s;
}

extern "C" void kernel_launch(void* const* d_in, const int* in_sizes, int n_in,
                              void* d_out, int out_size, void* d_ws, size_t ws_size,
                              hipStream_t stream) {
  const int*   ids  = (const int*)d_in[0];
  const float* mask = (const float*)d_in[1];
  const float* z    = (const float*)d_in[2];
  const float* tbl  = (const float*)d_in[3];
  const float* W1   = (const float*)d_in[4];
  const float* b1   = (const float*)d_in[5];
  const float* W2   = (const float*)d_in[6];
  const float* b2   = (const float*)d_in[7];
  const float* W3   = (const float*)d_in[8];
  const float* b3   = (const float*)d_in[9];
  const float* Wh   = (const float*)d_in[10];
  const float* bh   = (const float*)d_in[11];
  float* out  = (float*)d_out;
  float* part = (float*)d_ws;

  // Layout: part | x | a1q | a2 | a3.  x sits BEFORE the small weight arrays
  // so stage-1's 8-byte tail over-read (b=511,e=7,pos=2047) lands in a1q
  // (allocated, finite) instead of past the workspace.
  const size_t part_bytes = 1228800;                       // max(30,60)-layout
  const size_t x_bytes    = (size_t)512 * 8 * 4096 * 2;    // 32 MiB f16
  const size_t a1_bytes   = 8192;                          // [8][64][8] f16
  const size_t a_bytes    = 30720;                         // [30][64][8] f16
  const size_t need = part_bytes + x_bytes + a1_bytes + 2 * a_bytes;

  if (ws_size >= need) {
    f16* xh  = (f16*)((char*)d_ws + part_bytes);
    f16* a1q = (f16*)((char*)d_ws + part_bytes + x_bytes);
    f16* a2  = (f16*)((char*)d_ws + part_bytes + x_bytes + a1_bytes);
    f16* a3  = (f16*)((char*)d_ws + part_bytes + x_bytes + a1_bytes + a_bytes);
    hipLaunchKernelGGL(prep_kernel, dim3(1024 + 17), dim3(256), 0, stream,
                       ids, mask, tbl, W1, W2, W3, xh, a1q, a2, a3);
    hipLaunchKernelGGL(ensemble_f16_kernel, dim3(512 * 8), dim3(1024), 0, stream,
                       xh, a1q, a2, a3, z, b1, b2, b3, Wh, bh, part);
    hipLaunchKernelGGL(reduce30_kernel, dim3(20), dim3(256), 0, stream, part, out);
  } else {
    hipLaunchKernelGGL(ensemble_kernel, dim3(512 * 30 * 2), dim3(256), 0, stream,
                       ids, mask, z, tbl, W1, b1, W2, b2, W3, b3, Wh, bh, part);
    hipLaunchKernelGGL(reduce60_kernel, dim3(20), dim3(256), 0, stream, part, out);
  }
}

// Round 15
// 163.641 us; speedup vs baseline: 1.0338x; 1.0338x over previous
//
#include <hip/hip_runtime.h>
#include <stdint.h>

// FixedConv1DPriorEnsemble: DZ=30 ensemble of conv nets over embedded tokens.
// V=32000 E=8 DZ=30 C=10, CH=(4,8,8), K=3, S=(2,2,1), B=512, L=4096.
//
// History: R15 243.4; R16 1695 CATASTROPHIC (cross-XCD fences); R22 201.0
//   (d-PAIR @512thr); R23 187.2 (d-QUAD @1024thr); R24 342.6 CATASTROPHIC
//   (token-major x -> VMEM scatter); R25 186.3; R26 182.3; R27 174.8 (h2
//   pair-interleave); R28 171.0 (unwrapped h1 rot, conflicts -> 2.0M);
//   R29 168.5 (dead-wave guards, 4 barriers); R30 164.4 BEST (packed
//   cvt+relu, union B-frags, hoisted guard: ensemble 72.5, VALU 52%);
//   R31 169.2 (8-tok/thread prep REGRESSED +5: third data point proving
//   prep embed is gather-latency/TLP-bound -- wave count is the binding
//   resource, store count irrelevant).
// R32: revert prep embed to R30's 1-token/thread (8192 blocks, max waves);
//   ensemble frozen at R30 state. All levers on both kernels now probed:
//   ensemble at phase-serialized pipe floor (R28 proved conflict-
//   elimination time-neutral); prep at its latency floor; remaining gap
//   ~92us is fixed overhead (insensitive across prep variants).

typedef _Float16 f16;
typedef f16 f16x2 __attribute__((ext_vector_type(2)));
typedef f16 f16x4 __attribute__((ext_vector_type(4)));
typedef f16 f16x8 __attribute__((ext_vector_type(8)));
typedef float f32x4 __attribute__((ext_vector_type(4)));

#define H1ROWC 528   // h1 row size in f16x4 chunks (rot_max 15 + 513)
#define H1REGC 2112  // h1 region size in chunks (4 rows)
#define REGH   8448  // region size in f16 (= H1REGC*4); h2 uses 8224 of it
#define H2RS   2056  // h2 pair-row stride in f16 (4112B: 1024 cells + 16B pad)

// packed f32x2 -> f16x2 convert (RTZ) + packed ReLU
static __device__ __forceinline__ f16x2 cvtpk_relu(float a, float b) {
  auto r = __builtin_amdgcn_cvt_pkrtz(a, b);
  union { decltype(r) i; f16x2 o; } u; u.i = r;
  const f16x2 z2 = {(f16)0.0f, (f16)0.0f};
  return __builtin_elementwise_max(u.o, z2);   // v_pk_max_f16
}

// ---- prep: embed x_f16 (e-major) + stage-1 quad B-frags + a2/a3 ----
__global__ __launch_bounds__(256) void prep_kernel(
    const int* __restrict__ ids, const float* __restrict__ mask,
    const float* __restrict__ tbl,
    const float* __restrict__ W1, const float* __restrict__ W2,
    const float* __restrict__ W3,
    f16* __restrict__ x, f16* __restrict__ a1q,
    f16* __restrict__ a2, f16* __restrict__ a3) {
  const int blk = blockIdx.x;
  if (blk < 8192) {                            // embed: 1 token/thread
    const int b = blk >> 4;
    const int l = (blk & 15) * 256 + threadIdx.x;   // 0..4095
    const int   id = ids[(size_t)b * 4096 + l];
    const float m  = mask[(size_t)b * 4096 + l];
    const float4* t4 = (const float4*)tbl;
    const float4 va = t4[(size_t)id * 2];
    const float4 vb = t4[(size_t)id * 2 + 1];
    const float r[8] = {va.x, va.y, va.z, va.w, vb.x, vb.y, vb.z, vb.w};
    f16* xb = x + (size_t)b * 32768 + l;       // e-major: [b][e][4096]
    #pragma unroll
    for (int e = 0; e < 8; ++e)
      xb[e * 4096] = (f16)(r[e] * m);          // b16 store, lanes contiguous
  } else {
    const int i = (blk - 8192) * 256 + threadIdx.x;
    if (i < 512) {                             // a1q: 8 groups * 64 lanes
      // Stage-1 B-frag (E-MAJOR K-map): k = kg*8+j ->
      //   e = 2*kg + (j>>2), tap = j&3 (tap==3 slots zero: K pad 24->32).
      const int g = i >> 6, l = i & 63;
      const int kg = l >> 4, col = l & 15;
      const int d = 4 * g + (col >> 2);
      f16x8 v;
      #pragma unroll
      for (int j = 0; j < 8; ++j) {
        const int e = 2 * kg + (j >> 2), tap = j & 3;
        float val = 0.0f;
        if (tap < 3 && d < 30)
          val = W1[d * 96 + (col & 3) * 24 + e * 3 + tap];
        v[j] = (f16)val;
      }
      *(f16x8*)(a1q + ((size_t)g * 64 + l) * 8) = v;
    } else if (i < 2432) {                     // a2: 30*64
      const int idx = i - 512, d = idx >> 6, lane = idx & 63;
      const int quad = lane >> 4, m = lane & 15;
      f16x8 v;
      #pragma unroll
      for (int j = 0; j < 8; ++j) {
        float val = 0.0f;
        if (m < 8)  { if (j < 3)           val = W2[d * 96 + m * 12 + quad * 3 + j]; }
        else        { if (j >= 2 && j < 5) val = W2[d * 96 + (m - 8) * 12 + quad * 3 + (j - 2)]; }
        v[j] = (f16)val;
      }
      *(f16x8*)(a2 + ((size_t)d * 64 + lane) * 8) = v;
    } else if (i < 4352) {                     // a3: 30*64 (PAIR K-map)
      // K-slot j: row-sel = j&1 (c2 = quad*2 + (j&1)), tap index t = j>>1.
      const int idx = i - 2432, d = idx >> 6, lane = idx & 63;
      const int quad = lane >> 4, m = lane & 15;
      f16x8 v;
      #pragma unroll
      for (int j = 0; j < 8; ++j) {
        const int c2 = quad * 2 + (j & 1), t = j >> 1;
        float val = 0.0f;
        if (m < 8)  { if (t < 3)  val = W3[d * 192 + m * 24 + c2 * 3 + t]; }
        else        { if (t >= 1) val = W3[d * 192 + (m - 8) * 24 + c2 * 3 + (t - 1)]; }
        v[j] = (f16)val;
      }
      *(f16x8*)(a3 + ((size_t)d * 64 + lane) * 8) = v;
    }
  }
}

// ---------- fast path: one 1024-thread block per (b, d-quad group) ----------
__global__ __launch_bounds__(1024, 8) void ensemble_f16_kernel(
    const f16* __restrict__ x,        // [512][8][4096]  (e-major)
    const f16* __restrict__ a1q,      // stage-1 B-frags [8][64][8]
    const f16* __restrict__ a2,       // stage-2 A-frags [30][64][8]
    const f16* __restrict__ a3,       // stage-3 A-frags [30][64][8] (pair map)
    const float* __restrict__ z,
    const float* __restrict__ b1, const float* __restrict__ b2,
    const float* __restrict__ b3,
    const float* __restrict__ Wh, const float* __restrict__ bh,
    float* __restrict__ part)         // [30][512][10]
{
  const int tid = threadIdx.x;
  // XCD-bijective swizzle: 4096 = 8 XCDs x 512. All 8 same-b groups (and 64
  // consecutive b's) land on one XCD -> x row lives in that XCD's L2.
  const int swz = ((blockIdx.x & 7) * 512) + (blockIdx.x >> 3);
  const int b   = swz >> 3;           // 0..511
  const int G   = swz & 7;            // d-quad group: d = 4G .. 4G+3 (G=7: pair)
  const int d_base = 4 * G;

  // LDS: 4 regions x REGH f16 = 67584B + red2 512B.
  //   region g, h1: 4 rows x 528 chunks (f16x4); row data starts at chunk
  //     offset rot = row + 4*g; chunk rot+512 pre-zeroed (stage-2 +1 read).
  //   h2 overlay (post-B2): pair rows rp=0..3, stride H2RS f16.
  __shared__ __align__(16) f16 smemh[4 * REGH];
  __shared__ float red2[128];         // [4 groups][32]; NOT overlaid -> no B4

  const int w = tid >> 6, lane = tid & 63, quad = lane >> 4, n = lane & 15;
  const int gg = w >> 2, wv = w & 3;  // wave-group (d within quad), wave-in-group
  const int d  = d_base + gg;
  const int dc = d < 30 ? d : 29;     // clamp (loads before the live-guards)
  const bool live = (d < 30);         // G=7 gg=2,3: dead for stages 2/3

  // pre-zero the 16 read-but-never-written tail chunks (rot+512 per row)
  if (tid < 16) {
    f16x4 zz = {(f16)0.0f, (f16)0.0f, (f16)0.0f, (f16)0.0f};
    ((f16x4*)smemh)[(tid >> 2) * H1REGC + (tid & 3) * H1ROWC + tid + 512] = zz;
  }

  // ---- stage 1 (MFMA, ALL 16 waves, 4 d's): 128 tiles of 16 positions ----
  // A = patches (E-MAJOR): lane(row=n, kg=quad) holds x[e=2q..2q+1][2*pos+0..3],
  //   pos = 16t + n; tap-3 K-slots hit zero weights (x finite, no masking).
  // B = a1q (cols 0-15 = 4d x 4ch). D: lane(col=n, quad) -> one b64 write at
  //   chunk rot + 4t + quad, rot = n. Banks: (n+4t+q) mod 16 = perfect floor.
  // Position 2047 tail garbage-finite (feeds only masked jl=1023 column);
  //   b=511 tail over-read lands in a1q (allocated, finite).
  {
    const f16x8 bw1 = *(const f16x8*)(a1q + ((size_t)G * 64 + lane) * 8);
    const int dn  = d_base + (n >> 2);
    const int dnc = dn < 30 ? dn : 29;
    const float bias = b1[dnc * 4 + (n & 3)];
    const f32x4 c1i = {bias, bias, bias, bias};
    const char* xc = (const char*)x + (size_t)b * 65536 + quad * 16384 + 4 * n;
    f16x4* h1c = (f16x4*)smemh + (n >> 2) * H1REGC + (n & 3) * H1ROWC + n;
    #pragma unroll
    for (int i = 0; i < 8; ++i) {
      const int t = w + 16 * i;                // 0..127
      const uint32_t o = 64u * (uint32_t)t;
      union { f16x8 v; uint32_t dw[4]; } u;
      u.dw[0] = *(const uint32_t*)(xc + o);            // e0: taps 0,1
      u.dw[1] = *(const uint32_t*)(xc + o + 4);        // e0: tap 2 (+dead)
      u.dw[2] = *(const uint32_t*)(xc + o + 8192);     // e1: taps 0,1
      u.dw[3] = *(const uint32_t*)(xc + o + 8192 + 4); // e1: tap 2 (+dead)
      const f32x4 D = __builtin_amdgcn_mfma_f32_16x16x32_f16(u.v, bw1, c1i, 0, 0, 0);
      union { f16x4 p; f16x2 h[2]; } up;
      up.h[0] = cvtpk_relu(D[0], D[1]);        // v_cvt_pkrtz + v_pk_max
      up.h[1] = cvtpk_relu(D[2], D[3]);
      h1c[4 * t + quad] = up.p;                // ds_write_b64, mask-free
    }
  }
  __syncthreads();                     // B1: h1 writes -> h1 reads

  // ---- stage 2 (MFMA): wave-group gg handles d on region gg; 32 tiles ----
  // B-frag = h1[row=quad][chunks 16t+n, 16t+n+1] at offset rot = quad+4*gg.
  //   The +1 at t=31,n=15 reads the pre-zeroed chunk rot+512 (j>=5 zero-
  //   weighted for m<8; j=4 feeds only the masked jl=1023 column).
  f32x4 Ci[8];
  if (live) {
    const f16x8 af2 = *(const f16x8*)(a2 + ((size_t)dc * 64 + lane) * 8);
    const f32x4 cinit2 = *(const f32x4*)(b2 + dc * 8 + (quad & 1) * 4);
    const f16x4* h1r = (const f16x4*)smemh + gg * H1REGC + quad * H1ROWC
                     + (quad + 4 * gg);
    #pragma unroll
    for (int i = 0; i < 8; ++i) {
      const int t = wv + 4 * i;               // 0..31
      union { f16x8 v; f16x4 h[2]; } u;      // adjacent halves, no shuffle
      u.h[0] = h1r[16 * t + n];
      u.h[1] = h1r[16 * t + n + 1];
      Ci[i] = __builtin_amdgcn_mfma_f32_16x16x32_f16(af2, u.v, cinit2, 0, 0, 0);
    }
  }
  __syncthreads();                     // B2: all h1 reads done; overlay h2

  // ---- h2 write (pair cells): rows c2b..c2b+3 -> pairs rp0, rp0+1 at
  //   position jl = 32t+2n+shift; two packed ds_write_b32, rotation-free.
  if (live) {
    f16* h2b = smemh + gg * REGH;
    const int rp0   = (quad & 1) * 2;
    const int shift = quad >> 1;
    #pragma unroll
    for (int i = 0; i < 8; ++i) {
      const int t  = wv + 4 * i;
      const int jl = 32 * t + 2 * n + shift;   // 0..1023
      const f16x2 pA = cvtpk_relu(Ci[i][0], Ci[i][1]);
      const f16x2 pB = cvtpk_relu(Ci[i][2], Ci[i][3]);
      *(f16x2*)(h2b + rp0 * H2RS + jl * 2)       = pA;
      *(f16x2*)(h2b + (rp0 + 1) * H2RS + jl * 2) = pB;
    }
  }
  __syncthreads();                     // B3: h2 writes -> h2 reads

  // ---- stage 3 (MFMA) + pool + reduction (no barrier after: red2 disjoint) ----
  if (live) {
    float pool4[4] = {0.0f, 0.0f, 0.0f, 0.0f};
    const f16x8 af3 = *(const f16x8*)(a3 + ((size_t)dc * 64 + lane) * 8);
    const f32x4 cinit3 = *(const f32x4*)(b3 + dc * 8 + (quad & 1) * 4);
    const f16* h2r = smemh + gg * REGH + quad * H2RS;
    #pragma unroll
    for (int i = 0; i < 8; ++i) {
      const int t  = wv + 4 * i;              // 0..31
      const int p0 = 32 * t + 2 * n;          // 0..1022 (even)
      union { f16x8 v; f16x4 h[2]; } u;      // adjacent halves, no shuffle
      u.h[0] = *(const f16x4*)(h2r + p0 * 2);      // cells p0,p0+1
      u.h[1] = *(const f16x4*)(h2r + p0 * 2 + 4);  // cells p0+2,p0+3
      const f32x4 C = __builtin_amdgcn_mfma_f32_16x16x32_f16(af3, u.v, cinit3, 0, 0, 0);
      if (i < 7) {                            // pl = 32t+2n+s <= 895 < 1021
        #pragma unroll
        for (int r = 0; r < 4; ++r) pool4[r] += fmaxf(C[r], 0.0f);
      } else {
        const int pl = 32 * t + 2 * n + (quad >> 1);
        if (pl < 1021) {
          #pragma unroll
          for (int r = 0; r < 4; ++r) pool4[r] += fmaxf(C[r], 0.0f);
        }
      }
    }
    // shfl_xor butterfly over the 32 lanes sharing a cc-group (masks
    // 1,2,4,8,32 never touch lane bit 4); one write per (wave, cc-group).
    #pragma unroll
    for (int r = 0; r < 4; ++r) pool4[r] += __shfl_xor(pool4[r], 1, 64);
    #pragma unroll
    for (int r = 0; r < 4; ++r) pool4[r] += __shfl_xor(pool4[r], 2, 64);
    #pragma unroll
    for (int r = 0; r < 4; ++r) pool4[r] += __shfl_xor(pool4[r], 4, 64);
    #pragma unroll
    for (int r = 0; r < 4; ++r) pool4[r] += __shfl_xor(pool4[r], 8, 64);
    #pragma unroll
    for (int r = 0; r < 4; ++r) pool4[r] += __shfl_xor(pool4[r], 32, 64);
    if ((lane & 47) == 0) {      // lanes 0 (cc 0-3) and 16 (cc 4-7)
      const int cg = (lane >> 4) & 1;
      #pragma unroll
      for (int r = 0; r < 4; ++r)
        red2[gg * 32 + wv * 8 + cg * 4 + r] = pool4[r];
    }
  }
  __syncthreads();                     // B4: red2 writes -> head reads

  // ---- heads: waves 0,4,8,12 -> d = d_base + gg ----
  if ((w & 3) == 0 && lane < 10 && live) {
    float acc = bh[d * 10 + lane];
    #pragma unroll
    for (int c3 = 0; c3 < 8; ++c3) {
      const float pooled = red2[gg * 32 + c3]      + red2[gg * 32 + 8 + c3]
                         + red2[gg * 32 + 16 + c3] + red2[gg * 32 + 24 + c3];
      acc = fmaf(pooled * (1.0f / 1021.0f), Wh[d * 80 + lane * 8 + c3], acc);
    }
    part[((size_t)d * 512 + b) * 10 + lane] = z[d] * acc;
  }
}

// Fixed-order reduction over 30 d-partials: bitwise-deterministic.
__global__ __launch_bounds__(256) void reduce30_kernel(
    const float* __restrict__ part,   // [30][512][10]
    float* __restrict__ out)          // [512][10]
{
  const int i = blockIdx.x * 256 + threadIdx.x;   // 0..5119
  float s = 0.0f;
  #pragma unroll
  for (int dd = 0; dd < 30; ++dd) s += part[dd * 5120 + i];
  out[i] = s;
}

// ---------------- fallback path: exact R7 fp32 kernel (60 partials) ----------------
__global__ __launch_bounds__(256, 6) void ensemble_kernel(
    const int* __restrict__ ids, const float* __restrict__ mask,
    const float* __restrict__ z, const float* __restrict__ tbl,
    const float* __restrict__ W1, const float* __restrict__ b1,
    const float* __restrict__ W2, const float* __restrict__ b2,
    const float* __restrict__ W3, const float* __restrict__ b3,
    const float* __restrict__ Wh, const float* __restrict__ bh,
    float* __restrict__ part)
{
  const int tid  = threadIdx.x;
  const int half = blockIdx.x & 1;
  const int bd   = blockIdx.x >> 1;
  const int b    = bd & 511;
  const int d    = bd >> 9;

  __shared__ float smem[4128];
  __shared__ float red[32];
  __shared__ float pooled[8];

  const int l_lo = half ? 1024 : 0;
  const int l_hi = half ? 2047 : 1029;
  const int j_lo = half ? 512  : 0;
  const int j_hi = half ? 1023 : 514;
  const int o_lo = half ? 512  : 0;
  const int o_hi = half ? 1021 : 512;

  const int*    idrow = ids  + (size_t)b * 4096;
  const float*  mrow  = mask + (size_t)b * 4096;
  const float4* tbl4  = (const float4*)tbl;
  const float*  w1p = W1 + d * 96;
  const float*  w2p = W2 + d * 96;
  const float*  w3p = W3 + d * 192;

  {
    float bia[4];
    #pragma unroll
    for (int c = 0; c < 4; ++c) bia[c] = b1[d * 4 + c];

    #pragma unroll 1
    for (int pass = 0; pass < 2; ++pass) {
      const int l0 = l_lo + 2 * tid + 512 * pass;
      const int p0 = 2 * l0;
      const int4   iv = *(const int4*)(idrow + p0);
      const float4 mv = *(const float4*)(mrow + p0);
      int i4; float m4;
      if (p0 + 4 < 4096) { i4 = idrow[p0 + 4]; m4 = mrow[p0 + 4]; }
      else               { i4 = 0;              m4 = 0.0f; }

      const int   pid[5] = {iv.x, iv.y, iv.z, iv.w, i4};
      const float pm[5]  = {mv.x, mv.y, mv.z, mv.w, m4};

      float a0[4], a1v[4];
      #pragma unroll
      for (int c = 0; c < 4; ++c) { a0[c] = bia[c]; a1v[c] = bia[c]; }

      #pragma unroll
      for (int q = 0; q < 5; ++q) {
        const float4 va = tbl4[(size_t)pid[q] * 2];
        const float4 vb = tbl4[(size_t)pid[q] * 2 + 1];
        const float xe[8] = {va.x * pm[q], va.y * pm[q], va.z * pm[q], va.w * pm[q],
                             vb.x * pm[q], vb.y * pm[q], vb.z * pm[q], vb.w * pm[q]};
        if (q <= 2) {
          #pragma unroll
          for (int c = 0; c < 4; ++c)
            #pragma unroll
            for (int e = 0; e < 8; ++e)
              a0[c] = fmaf(xe[e], w1p[c * 24 + e * 3 + q], a0[c]);
        }
        if (q >= 2) {
          #pragma unroll
          for (int c = 0; c < 4; ++c)
            #pragma unroll
            for (int e = 0; e < 8; ++e)
              a1v[c] = fmaf(xe[e], w1p[c * 24 + e * 3 + (q - 2)], a1v[c]);
        }
      }
      const int rel = l0 - l_lo;
      if (l0 + 1 < l_hi) {
        #pragma unroll
        for (int c = 0; c < 4; ++c)
          *(float2*)(smem + c * 1032 + rel) =
              make_float2(fmaxf(a0[c], 0.0f), fmaxf(a1v[c], 0.0f));
      } else if (l0 < l_hi) {
        #pragma unroll
        for (int c = 0; c < 4; ++c)
          smem[c * 1032 + rel] = fmaxf(a0[c], 0.0f);
      }
    }
    const int lt = l_lo + 1024 + tid;
    if (lt < l_hi) {
      float a0[4];
      #pragma unroll
      for (int c = 0; c < 4; ++c) a0[c] = bia[c];
      #pragma unroll
      for (int k = 0; k < 3; ++k) {
        const int p = 2 * lt + k;
        const int id = idrow[p];
        const float m = mrow[p];
        const float4 va = tbl4[(size_t)id * 2];
        const float4 vb = tbl4[(size_t)id * 2 + 1];
        const float xe[8] = {va.x*m, va.y*m, va.z*m, va.w*m,
                             vb.x*m, vb.y*m, vb.z*m, vb.w*m};
        #pragma unroll
        for (int cc = 0; cc < 4; ++cc)
          #pragma unroll
          for (int e = 0; e < 8; ++e)
            a0[cc] = fmaf(xe[e], w1p[cc * 24 + e * 3 + k], a0[cc]);
      }
      #pragma unroll
      for (int c = 0; c < 4; ++c)
        smem[c * 1032 + 1024 + tid] = fmaxf(a0[c], 0.0f);
    }
  }
  __syncthreads();

  float acc2[8][2], acc2t[8];
  {
    #pragma unroll
    for (int c2 = 0; c2 < 8; ++c2) {
      const float bb = b2[d * 8 + c2];
      acc2[c2][0] = bb; acc2[c2][1] = bb; acc2t[c2] = bb;
    }
    const int rel2  = 4 * tid;
    const bool tail2 = tid < (j_hi - j_lo - 512);
    #pragma unroll 1
    for (int c1 = 0; c1 < 4; ++c1) {
      float sw[8][3];
      #pragma unroll
      for (int c2 = 0; c2 < 8; ++c2)
        #pragma unroll
        for (int kk = 0; kk < 3; ++kk)
          sw[c2][kk] = w2p[c2 * 12 + c1 * 3 + kk];
      const float* hp = smem + c1 * 1032;
      const float4 h01 = *(const float4*)(hp + rel2);
      const float  h4v = hp[rel2 + 4];
      #pragma unroll
      for (int c2 = 0; c2 < 8; ++c2) {
        acc2[c2][0] = fmaf(h01.x, sw[c2][0], fmaf(h01.y, sw[c2][1],
                      fmaf(h01.z, sw[c2][2], acc2[c2][0])));
        acc2[c2][1] = fmaf(h01.z, sw[c2][0], fmaf(h01.w, sw[c2][1],
                      fmaf(h4v,   sw[c2][2], acc2[c2][1])));
      }
      if (tail2) {
        const float t0 = hp[1024 + 2 * tid], t1 = hp[1025 + 2 * tid],
                    t2 = hp[1026 + 2 * tid];
        #pragma unroll
        for (int c2 = 0; c2 < 8; ++c2)
          acc2t[c2] = fmaf(t0, sw[c2][0], fmaf(t1, sw[c2][1],
                      fmaf(t2, sw[c2][2], acc2t[c2])));
      }
    }
    #pragma unroll
    for (int c2 = 0; c2 < 8; ++c2) {
      acc2[c2][0] = fmaxf(acc2[c2][0], 0.0f);
      acc2[c2][1] = fmaxf(acc2[c2][1], 0.0f);
      acc2t[c2]   = fmaxf(acc2t[c2],   0.0f);
    }
    __syncthreads();
    const int j0 = j_lo + 2 * tid;
    const int jr = 2 * tid;
    if (j0 + 1 < j_hi) {
      #pragma unroll
      for (int c2 = 0; c2 < 8; ++c2)
        *(float2*)(smem + c2 * 516 + jr) = make_float2(acc2[c2][0], acc2[c2][1]);
    } else if (j0 < j_hi) {
      #pragma unroll
      for (int c2 = 0; c2 < 8; ++c2)
        smem[c2 * 516 + jr] = acc2[c2][0];
    }
    if (tid < (j_hi - j_lo - 512)) {
      #pragma unroll
      for (int c2 = 0; c2 < 8; ++c2)
        smem[c2 * 516 + 512 + tid] = acc2t[c2];
    }
  }
  __syncthreads();

  float acc3[8][2];
  #pragma unroll
  for (int cc = 0; cc < 8; ++cc) {
    const float bb = b3[d * 8 + cc];
    acc3[cc][0] = bb; acc3[cc][1] = bb;
  }
  {
    const int rel3 = 2 * tid;
    #pragma unroll 1
    for (int c2 = 0; c2 < 8; ++c2) {
      float sw[8][3];
      #pragma unroll
      for (int cc = 0; cc < 8; ++cc)
        #pragma unroll
        for (int kk = 0; kk < 3; ++kk)
          sw[cc][kk] = w3p[cc * 24 + c2 * 3 + kk];
      const float* hp = smem + c2 * 516;
      const float2 ha = *(const float2*)(hp + rel3);
      const float2 hb = *(const float2*)(hp + rel3 + 2);
      #pragma unroll
      for (int cc = 0; cc < 8; ++cc) {
        acc3[cc][0] = fmaf(ha.x, sw[cc][0], fmaf(ha.y, sw[cc][1],
                      fmaf(hb.x, sw[cc][2], acc3[cc][0])));
        acc3[cc][1] = fmaf(ha.y, sw[cc][0], fmaf(hb.x, sw[cc][1],
                      fmaf(hb.y, sw[cc][2], acc3[cc][1])));
      }
    }
  }
  const int i0 = o_lo + 2 * tid;
  float psum[8];
  #pragma unroll
  for (int cc = 0; cc < 8; ++cc) {
    float s = 0.0f;
    if (i0 < o_hi)     s += fmaxf(acc3[cc][0], 0.0f);
    if (i0 + 1 < o_hi) s += fmaxf(acc3[cc][1], 0.0f);
    psum[cc] = s;
  }

  const int lane = tid & 63;
  const int wid  = tid >> 6;
  #pragma unroll
  for (int c = 0; c < 8; ++c) {
    float v = psum[c];
    #pragma unroll
    for (int off = 32; off > 0; off >>= 1) v += __shfl_down(v, off, 64);
    if (lane == 0) red[wid * 8 + c] = v;
  }
  __syncthreads();
  if (tid < 8)
    pooled[tid] = red[tid] + red[8 + tid] + red[16 + tid] + red[24 + tid];
  __syncthreads();

  if (tid < 10) {
    float acc = (half == 0) ? bh[d * 10 + tid] : 0.0f;
    #pragma unroll
    for (int c3 = 0; c3 < 8; ++c3)
      acc = fmaf(pooled[c3] * (1.0f / 1021.0f), Wh[d * 80 + tid * 8 + c3], acc);
    part[(((size_t)d * 2 + half) * 512 + b) * 10 + tid] = z[d] * acc;
  }
}

__global__ __launch_bounds__(256) void reduce60_kernel(
    const float* __restrict__ part,   // [60][512][10]
    float* __restrict__ out)          // [512][10]
{
  const int i = blockIdx.x * 256 + threadIdx.x;
  float s = 0.0f;
  #pragma unroll
  for (int dd = 0; dd < 60; ++dd) s += part[dd * 5120 + i];
  out[i] = s;
}

extern "C" void kernel_launch(void* const* d_in, const int* in_sizes, int n_in,
                              void* d_out, int out_size, void* d_ws, size_t ws_size,
                              hipStream_t stream) {
  const int*   ids  = (const int*)d_in[0];
  const float* mask = (const float*)d_in[1];
  const float* z    = (const float*)d_in[2];
  const float* tbl  = (const float*)d_in[3];
  const float* W1   = (const float*)d_in[4];
  const float* b1   = (const float*)d_in[5];
  const float* W2   = (const float*)d_in[6];
  const float* b2   = (const float*)d_in[7];
  const float* W3   = (const float*)d_in[8];
  const float* b3   = (const float*)d_in[9];
  const float* Wh   = (const float*)d_in[10];
  const float* bh   = (const float*)d_in[11];
  float* out  = (float*)d_out;
  float* part = (float*)d_ws;

  // Layout: part | x | a1q | a2 | a3.  x sits BEFORE the small weight arrays
  // so stage-1's 8-byte tail over-read (b=511,e=7,pos=2047) lands in a1q
  // (allocated, finite) instead of past the workspace.
  const size_t part_bytes = 1228800;                       // max(30,60)-layout
  const size_t x_bytes    = (size_t)512 * 8 * 4096 * 2;    // 32 MiB f16
  const size_t a1_bytes   = 8192;                          // [8][64][8] f16
  const size_t a_bytes    = 30720;                         // [30][64][8] f16
  const size_t need = part_bytes + x_bytes + a1_bytes + 2 * a_bytes;

  if (ws_size >= need) {
    f16* xh  = (f16*)((char*)d_ws + part_bytes);
    f16* a1q = (f16*)((char*)d_ws + part_bytes + x_bytes);
    f16* a2  = (f16*)((char*)d_ws + part_bytes + x_bytes + a1_bytes);
    f16* a3  = (f16*)((char*)d_ws + part_bytes + x_bytes + a1_bytes + a_bytes);
    hipLaunchKernelGGL(prep_kernel, dim3(8192 + 17), dim3(256), 0, stream,
                       ids, mask, tbl, W1, W2, W3, xh, a1q, a2, a3);
    hipLaunchKernelGGL(ensemble_f16_kernel, dim3(512 * 8), dim3(1024), 0, stream,
                       xh, a1q, a2, a3, z, b1, b2, b3, Wh, bh, part);
    hipLaunchKernelGGL(reduce30_kernel, dim3(20), dim3(256), 0, stream, part, out);
  } else {
    hipLaunchKernelGGL(ensemble_kernel, dim3(512 * 30 * 2), dim3(256), 0, stream,
                       ids, mask, z, tbl, W1, b1, W2, b2, W3, b3, Wh, bh, part);
    hipLaunchKernelGGL(reduce60_kernel, dim3(20), dim3(256), 0, stream, part, out);
  }
}